// Round 1
// baseline (1840.400 us; speedup 1.0000x reference)
//
#include <hip/hip_runtime.h>
#include <hip/hip_bf16.h>

// Problem constants (SwinAttention: B=2048, S=49, D=384, H=12, hd=32)
#define BATCH 2048
#define SEQ   49
#define DIM   384
#define HEADS 12
#define HD    32
#define ROWS  (BATCH*SEQ)      // 100352
#define QKVD  (3*DIM)          // 1152

// ---------------- GEMM: C[M,N] = A[M,K] * W[N,K]^T + bias[N] ----------------
// BM=BN=128, BK=16, 256 threads, 8x8 per thread (split 4+4 with 64 offset).
#define BM 128
#define BN 128
#define BK 16
#define LDT 132   // padded leading dim for LDS tiles

__global__ __launch_bounds__(256) void gemm_nt_bias(
    const float* __restrict__ A, const float* __restrict__ W,
    const float* __restrict__ bias, float* __restrict__ C,
    int M, int N, int K)
{
    __shared__ float As[BK][LDT];
    __shared__ float Bs[BK][LDT];

    const int tid  = threadIdx.x;
    const int row0 = blockIdx.y * BM;
    const int col0 = blockIdx.x * BN;
    const int tm   = tid >> 4;   // 0..15
    const int tn   = tid & 15;   // 0..15

    float acc[8][8];
#pragma unroll
    for (int i = 0; i < 8; ++i)
#pragma unroll
        for (int j = 0; j < 8; ++j) acc[i][j] = 0.f;

    for (int k0 = 0; k0 < K; k0 += BK) {
        __syncthreads();
        // stage A and W tiles: 128 rows x 16 k each, as [k][m] in LDS
#pragma unroll
        for (int f = tid; f < (BM*BK)/4; f += 256) {
            int m = f >> 2, c = f & 3;
            float4 a = *(const float4*)(A + (size_t)(row0 + m)*K + k0 + c*4);
            As[c*4+0][m] = a.x; As[c*4+1][m] = a.y;
            As[c*4+2][m] = a.z; As[c*4+3][m] = a.w;
            float4 b = *(const float4*)(W + (size_t)(col0 + m)*K + k0 + c*4);
            Bs[c*4+0][m] = b.x; Bs[c*4+1][m] = b.y;
            Bs[c*4+2][m] = b.z; Bs[c*4+3][m] = b.w;
        }
        __syncthreads();

#pragma unroll
        for (int k = 0; k < BK; ++k) {
            float a[8], b[8];
            *(float4*)&a[0] = *(const float4*)&As[k][tm*4];
            *(float4*)&a[4] = *(const float4*)&As[k][tm*4 + 64];
            *(float4*)&b[0] = *(const float4*)&Bs[k][tn*4];
            *(float4*)&b[4] = *(const float4*)&Bs[k][tn*4 + 64];
#pragma unroll
            for (int i = 0; i < 8; ++i)
#pragma unroll
                for (int j = 0; j < 8; ++j)
                    acc[i][j] += a[i]*b[j];
        }
    }

    float4 bv0 = *(const float4*)(bias + col0 + tn*4);
    float4 bv1 = *(const float4*)(bias + col0 + tn*4 + 64);
#pragma unroll
    for (int i = 0; i < 8; ++i) {
        int r = row0 + tm*4 + ((i < 4) ? i : 64 + (i - 4));
        float4 o0, o1;
        o0.x = acc[i][0] + bv0.x; o0.y = acc[i][1] + bv0.y;
        o0.z = acc[i][2] + bv0.z; o0.w = acc[i][3] + bv0.w;
        o1.x = acc[i][4] + bv1.x; o1.y = acc[i][5] + bv1.y;
        o1.z = acc[i][6] + bv1.z; o1.w = acc[i][7] + bv1.w;
        *(float4*)(C + (size_t)r*N + col0 + tn*4)      = o0;
        *(float4*)(C + (size_t)r*N + col0 + tn*4 + 64) = o1;
    }
}

// ---------------- Attention: one block (64 thr) per (window, head) ----------
__global__ __launch_bounds__(64) void attn_kernel(
    const float* __restrict__ qkv, const float* __restrict__ mask,
    const float* __restrict__ table, float* __restrict__ out)
{
    const int bh = blockIdx.x;
    const int b  = bh / HEADS;
    const int h  = bh % HEADS;
    const int tid = threadIdx.x;

    __shared__ float k_lds[SEQ][36];   // pad 36: keeps 16B alignment for b128
    __shared__ float v_lds[SEQ][36];
    __shared__ float bias_lds[169];    // (2*7-1)^2 entries for this head

    const size_t qbase = (size_t)b * SEQ * QKVD;

    // stage K, V (coalesced: 2 rows of 32 per wave-read)
    for (int e = tid; e < SEQ*HD; e += 64) {
        int s = e >> 5, d = e & 31;
        k_lds[s][d] = qkv[qbase + (size_t)s*QKVD + DIM     + h*HD + d];
        v_lds[s][d] = qkv[qbase + (size_t)s*QKVD + 2*DIM   + h*HD + d];
    }
    for (int e = tid; e < 169; e += 64)
        bias_lds[e] = table[e*HEADS + h];
    __syncthreads();

    if (tid < SEQ) {
        const int i = tid;
        const float scale = 0.17677669529663687f;  // 32^-0.5
        float q[HD];
#pragma unroll
        for (int d4 = 0; d4 < HD/4; ++d4) {
            float4 t = *(const float4*)(qkv + qbase + (size_t)i*QKVD + h*HD + d4*4);
            q[d4*4+0] = t.x*scale; q[d4*4+1] = t.y*scale;
            q[d4*4+2] = t.z*scale; q[d4*4+3] = t.w*scale;
        }
        const float* mrow = mask + ((size_t)b*SEQ + i)*SEQ;
        const int ri = i / 7, ci = i % 7;

        float s[SEQ];
#pragma unroll
        for (int j = 0; j < SEQ; ++j) {
            float dot = 0.f;
#pragma unroll
            for (int d = 0; d < HD; ++d) dot += q[d]*k_lds[j][d];
            int rj = j / 7, cj = j % 7;
            int ridx = (ri - rj + 6)*13 + (ci - cj + 6);
            s[j] = dot + bias_lds[ridx] + mrow[j];
        }

        float m = s[0];
#pragma unroll
        for (int j = 1; j < SEQ; ++j) m = fmaxf(m, s[j]);
        float sum = 0.f;
#pragma unroll
        for (int j = 0; j < SEQ; ++j) { float p = __expf(s[j]-m); s[j] = p; sum += p; }
        float inv = 1.0f / sum;

        float acc[HD];
#pragma unroll
        for (int d = 0; d < HD; ++d) acc[d] = 0.f;
#pragma unroll
        for (int j = 0; j < SEQ; ++j) {
            float p = s[j];
#pragma unroll
            for (int d = 0; d < HD; ++d) acc[d] += p * v_lds[j][d];
        }

        float* orow = out + ((size_t)b*SEQ + i)*DIM + h*HD;
#pragma unroll
        for (int d4 = 0; d4 < HD/4; ++d4) {
            float4 t;
            t.x = acc[d4*4+0]*inv; t.y = acc[d4*4+1]*inv;
            t.z = acc[d4*4+2]*inv; t.w = acc[d4*4+3]*inv;
            *(float4*)(orow + d4*4) = t;
        }
    }
}

// ---------------- launch ----------------------------------------------------
extern "C" void kernel_launch(void* const* d_in, const int* in_sizes, int n_in,
                              void* d_out, int out_size, void* d_ws, size_t ws_size,
                              hipStream_t stream) {
    const float* hidden = (const float*)d_in[0];  // [B,S,D]
    const float* mask   = (const float*)d_in[1];  // [B,S,S]
    const float* w_qkv  = (const float*)d_in[2];  // [3D,D]
    const float* b_qkv  = (const float*)d_in[3];  // [3D]
    const float* w_out  = (const float*)d_in[4];  // [D,D]
    const float* b_out  = (const float*)d_in[5];  // [D]
    const float* table  = (const float*)d_in[6];  // [169,H]
    float* out = (float*)d_out;

    float* qkv  = (float*)d_ws;                         // [ROWS, 1152] = 462.4 MB
    float* attn = qkv + (size_t)ROWS * QKVD;            // [ROWS, 384]  = 154.1 MB

    // 1) qkv = hidden @ w_qkv^T + b_qkv
    dim3 g1(QKVD / BN, ROWS / BM);   // (9, 784)
    gemm_nt_bias<<<g1, 256, 0, stream>>>(hidden, w_qkv, b_qkv, qkv, ROWS, QKVD, DIM);

    // 2) windowed attention per (b, h)
    attn_kernel<<<BATCH*HEADS, 64, 0, stream>>>(qkv, mask, table, attn);

    // 3) out = attn @ w_out^T + b_out
    dim3 g2(DIM / BN, ROWS / BM);    // (3, 784)
    gemm_nt_bias<<<g2, 256, 0, stream>>>(attn, w_out, b_out, out, ROWS, DIM, DIM);
}

// Round 2
// 1107.260 us; speedup vs baseline: 1.6621x; 1.6621x over previous
//
#include <hip/hip_runtime.h>

// SwinAttention: B=2048, S=49, D=384, H=12, hd=32 — all fp32 in/out.
#define BATCH 2048
#define SEQ   49
#define DIM   384
#define HEADS 12
#define HD    32
#define ROWS  (BATCH*SEQ)      // 100352 = 128*784
#define QKVD  (3*DIM)          // 1152

typedef __bf16 bf16x8 __attribute__((ext_vector_type(8)));
typedef float  f32x4  __attribute__((ext_vector_type(4)));
typedef unsigned short u16;
typedef unsigned short u16x4 __attribute__((ext_vector_type(4)));

__device__ __forceinline__ u16 f2bf(float f) {      // RNE float->bf16
    union { float f; unsigned u; } a; a.f = f;
    unsigned r = a.u + 0x7FFFu + ((a.u >> 16) & 1u);
    return (u16)(r >> 16);
}
__device__ __forceinline__ float bf2f(u16 u) {
    union { unsigned u; float f; } a; a.u = ((unsigned)u) << 16;
    return a.f;
}

// ---------------- fp32 -> bf16 convert (vectorized, grid-stride) ------------
__global__ void cvt_f32_bf16(const float* __restrict__ in, u16* __restrict__ out, int n4) {
    int stride = gridDim.x * blockDim.x;
    for (int i = blockIdx.x * blockDim.x + threadIdx.x; i < n4; i += stride) {
        f32x4 v = ((const f32x4*)in)[i];
        u16x4 o;
        o[0] = f2bf(v[0]); o[1] = f2bf(v[1]); o[2] = f2bf(v[2]); o[3] = f2bf(v[3]);
        ((u16x4*)out)[i] = o;
    }
}

// ---------------- bf16 MFMA GEMM: C[M,N] = A[M,K]·W[N,K]^T + bias -----------
// m97 structure: 128x128 tile, BK=32, 256 thr (4 waves 2x2), global_load_lds(16B),
// LDS linear [128][32] bf16 (gload_lds needs linear dest), 16 MFMA/K-step.
template <bool BF16_OUT>
__global__ __launch_bounds__(256) void gemm_bf16_nt(
    const u16* __restrict__ A, const u16* __restrict__ W,
    const float* __restrict__ bias, void* __restrict__ Cv,
    int M, int N, int K)
{
    __shared__ u16 Asm[128*32];
    __shared__ u16 Bsm[128*32];

    const int tid  = threadIdx.x;
    const int lane = tid & 63;
    const int wid  = tid >> 6;
    const int row0 = blockIdx.y * 128;
    const int col0 = blockIdx.x * 128;
    const int wr = (wid >> 1) * 64;   // wave's 64x64 sub-tile
    const int wc = (wid & 1) * 64;

    f32x4 acc[4][4] = {};

    // staging: wave w covers rows [w*16, w*16+16) and [64+w*16, ...). Lane l:
    // row = base + l/4, 16B k-chunk = l%4  (matches linear LDS dest base+lane*16).
    const int srow   = wid * 16 + (lane >> 2);
    const int kchunk = (lane & 3) * 8;           // bf16 elements

    for (int k0 = 0; k0 < K; k0 += 32) {
        __syncthreads();
        {
            const u16* ga0 = A + (size_t)(row0 + srow) * K + k0 + kchunk;
            const u16* ga1 = A + (size_t)(row0 + 64 + srow) * K + k0 + kchunk;
            const u16* gb0 = W + (size_t)(col0 + srow) * K + k0 + kchunk;
            const u16* gb1 = W + (size_t)(col0 + 64 + srow) * K + k0 + kchunk;
            __builtin_amdgcn_global_load_lds((const __attribute__((address_space(1))) void*)ga0,
                (__attribute__((address_space(3))) void*)&Asm[(wid*16)*32], 16, 0, 0);
            __builtin_amdgcn_global_load_lds((const __attribute__((address_space(1))) void*)ga1,
                (__attribute__((address_space(3))) void*)&Asm[(64 + wid*16)*32], 16, 0, 0);
            __builtin_amdgcn_global_load_lds((const __attribute__((address_space(1))) void*)gb0,
                (__attribute__((address_space(3))) void*)&Bsm[(wid*16)*32], 16, 0, 0);
            __builtin_amdgcn_global_load_lds((const __attribute__((address_space(1))) void*)gb1,
                (__attribute__((address_space(3))) void*)&Bsm[(64 + wid*16)*32], 16, 0, 0);
        }
        __syncthreads();   // compiler emits vmcnt(0) drain before barrier

        bf16x8 a[4], b[4];
#pragma unroll
        for (int m = 0; m < 4; ++m)
            a[m] = *(const bf16x8*)&Asm[(wr + m*16 + (lane & 15))*32 + (lane >> 4)*8];
#pragma unroll
        for (int n = 0; n < 4; ++n)
            b[n] = *(const bf16x8*)&Bsm[(wc + n*16 + (lane & 15))*32 + (lane >> 4)*8];
#pragma unroll
        for (int m = 0; m < 4; ++m)
#pragma unroll
            for (int n = 0; n < 4; ++n)
                acc[m][n] = __builtin_amdgcn_mfma_f32_16x16x32_bf16(a[m], b[n], acc[m][n], 0, 0, 0);
    }

    // epilogue: C/D layout col=lane&15, row=(lane>>4)*4+j  [m89-verified]
    const int rbase = row0 + wr + (lane >> 4) * 4;
    const int cbase = col0 + wc + (lane & 15);
#pragma unroll
    for (int n = 0; n < 4; ++n) {
        const int col = cbase + n*16;
        const float bv = bias[col];
#pragma unroll
        for (int m = 0; m < 4; ++m)
#pragma unroll
            for (int j = 0; j < 4; ++j) {
                const int row = rbase + m*16 + j;
                float v = acc[m][n][j] + bv;
                if constexpr (BF16_OUT) ((u16*)Cv)[(size_t)row * N + col] = f2bf(v);
                else                    ((float*)Cv)[(size_t)row * N + col] = v;
            }
    }
}

// ---------------- Attention: one 64-thr block per (window, head) ------------
// fp32 compute; bf16 in (qkv) / bf16 out (attn). float4 LDS reads, mask in LDS.
__global__ __launch_bounds__(64) void attn_kernel(
    const u16* __restrict__ qkv, const float* __restrict__ mask,
    const float* __restrict__ table, u16* __restrict__ out)
{
    const int bh = blockIdx.x;
    const int b  = bh / HEADS;
    const int h  = bh % HEADS;
    const int tid = threadIdx.x;

    __shared__ float k_lds[SEQ][36];    // 36 floats = 144B row, 16B-aligned
    __shared__ float v_lds[SEQ][36];
    __shared__ float m_lds[SEQ*SEQ];    // 9.6 KB
    __shared__ float bias_lds[169];

    const size_t qbase = (size_t)b * SEQ * QKVD;

    // stage K, V (2 bf16 per thread-elem, coalesced-ish)
    for (int e = tid; e < SEQ*HD/2; e += 64) {
        int s = e >> 4, d2 = (e & 15) * 2;
        unsigned kk = *(const unsigned*)&qkv[qbase + (size_t)s*QKVD + DIM   + h*HD + d2];
        unsigned vv = *(const unsigned*)&qkv[qbase + (size_t)s*QKVD + 2*DIM + h*HD + d2];
        k_lds[s][d2]   = bf2f((u16)(kk & 0xFFFF));
        k_lds[s][d2+1] = bf2f((u16)(kk >> 16));
        v_lds[s][d2]   = bf2f((u16)(vv & 0xFFFF));
        v_lds[s][d2+1] = bf2f((u16)(vv >> 16));
    }
    const float* mbase = mask + (size_t)b * SEQ * SEQ;
    for (int e = tid; e < SEQ*SEQ; e += 64) m_lds[e] = mbase[e];
    for (int e = tid; e < 169; e += 64)     bias_lds[e] = table[e*HEADS + h];
    __syncthreads();

    if (tid < SEQ) {
        const int i = tid;
        const float scale = 0.17677669529663687f;  // 32^-0.5
        float q[HD];
        const u16* qrow = &qkv[qbase + (size_t)i*QKVD + h*HD];
#pragma unroll
        for (int d8 = 0; d8 < 4; ++d8) {
            uint4 t = *(const uint4*)&qrow[d8*8];
            q[d8*8+0] = bf2f((u16)(t.x & 0xFFFF))*scale; q[d8*8+1] = bf2f((u16)(t.x >> 16))*scale;
            q[d8*8+2] = bf2f((u16)(t.y & 0xFFFF))*scale; q[d8*8+3] = bf2f((u16)(t.y >> 16))*scale;
            q[d8*8+4] = bf2f((u16)(t.z & 0xFFFF))*scale; q[d8*8+5] = bf2f((u16)(t.z >> 16))*scale;
            q[d8*8+6] = bf2f((u16)(t.w & 0xFFFF))*scale; q[d8*8+7] = bf2f((u16)(t.w >> 16))*scale;
        }
        const int ri = i / 7, ci = i % 7;

        float s[SEQ];
#pragma unroll
        for (int j = 0; j < SEQ; ++j) {
            float dot = 0.f;
#pragma unroll
            for (int d4 = 0; d4 < 8; ++d4) {
                f32x4 kv = *(const f32x4*)&k_lds[j][d4*4];   // ds_read_b128 broadcast
                dot += q[d4*4+0]*kv[0] + q[d4*4+1]*kv[1] + q[d4*4+2]*kv[2] + q[d4*4+3]*kv[3];
            }
            int rj = j / 7, cj = j % 7;
            s[j] = dot + bias_lds[(ri-rj+6)*13 + (ci-cj+6)] + m_lds[i*SEQ + j];
        }

        float m = s[0];
#pragma unroll
        for (int j = 1; j < SEQ; ++j) m = fmaxf(m, s[j]);
        float sum = 0.f;
#pragma unroll
        for (int j = 0; j < SEQ; ++j) { float p = __expf(s[j]-m); s[j] = p; sum += p; }
        float inv = 1.0f / sum;

        f32x4 a4[8] = {};
#pragma unroll
        for (int j = 0; j < SEQ; ++j) {
            float p = s[j];
#pragma unroll
            for (int d4 = 0; d4 < 8; ++d4) {
                f32x4 vv = *(const f32x4*)&v_lds[j][d4*4];
                a4[d4] += p * vv;
            }
        }

        u16* orow = out + ((size_t)b*SEQ + i)*DIM + h*HD;
#pragma unroll
        for (int d4 = 0; d4 < 8; ++d4) {
            u16x4 o;
            o[0] = f2bf(a4[d4][0]*inv); o[1] = f2bf(a4[d4][1]*inv);
            o[2] = f2bf(a4[d4][2]*inv); o[3] = f2bf(a4[d4][3]*inv);
            *(u16x4*)&orow[d4*4] = o;
        }
    }
}

// ---------------- launch ----------------------------------------------------
extern "C" void kernel_launch(void* const* d_in, const int* in_sizes, int n_in,
                              void* d_out, int out_size, void* d_ws, size_t ws_size,
                              hipStream_t stream) {
    const float* hidden = (const float*)d_in[0];
    const float* mask   = (const float*)d_in[1];
    const float* w_qkv  = (const float*)d_in[2];
    const float* b_qkv  = (const float*)d_in[3];
    const float* w_out  = (const float*)d_in[4];
    const float* b_out  = (const float*)d_in[5];
    const float* table  = (const float*)d_in[6];
    float* out = (float*)d_out;

    char* ws = (char*)d_ws;
    u16* hiddenb = (u16*)ws;  ws += (size_t)ROWS*DIM*2;    // 77.1 MB
    u16* wqkvb   = (u16*)ws;  ws += (size_t)QKVD*DIM*2;    // 0.88 MB
    u16* woutb   = (u16*)ws;  ws += (size_t)DIM*DIM*2;     // 0.29 MB
    u16* qkvb    = (u16*)ws;  ws += (size_t)ROWS*QKVD*2;   // 231.2 MB
    u16* attnb   = (u16*)ws;                               // 77.1 MB  (total 386.6 MB)

    // converts
    cvt_f32_bf16<<<2048, 256, 0, stream>>>(hidden, hiddenb, ROWS*DIM/4);
    cvt_f32_bf16<<<432,  256, 0, stream>>>(w_qkv,  wqkvb,   QKVD*DIM/4);
    cvt_f32_bf16<<<144,  256, 0, stream>>>(w_out,  woutb,   DIM*DIM/4);

    // 1) qkv = hidden @ w_qkv^T + b_qkv   (bf16 out)
    dim3 g1(QKVD / 128, ROWS / 128);   // (9, 784)
    gemm_bf16_nt<true><<<g1, 256, 0, stream>>>(hiddenb, wqkvb, b_qkv, qkvb, ROWS, QKVD, DIM);

    // 2) windowed attention per (b, h)   (bf16 out)
    attn_kernel<<<BATCH*HEADS, 64, 0, stream>>>(qkvb, mask, table, attnb);

    // 3) out = attn @ w_out^T + b_out    (fp32 out -> d_out)
    dim3 g2(DIM / 128, ROWS / 128);    // (3, 784)
    gemm_bf16_nt<false><<<g2, 256, 0, stream>>>(attnb, woutb, b_out, out, ROWS, DIM, DIM);
}

// Round 4
// 825.048 us; speedup vs baseline: 2.2307x; 1.3421x over previous
//
#include <hip/hip_runtime.h>

// SwinAttention: B=2048, S=49, D=384, H=12, hd=32 — fp32 in/out.
#define BATCH 2048
#define SEQ   49
#define DIM   384
#define HEADS 12
#define HD    32
#define ROWS  (BATCH*SEQ)      // 100352 = 128*784
#define QKVD  (3*DIM)          // 1152

typedef __bf16 bf16x8 __attribute__((ext_vector_type(8)));
typedef float  f32x4  __attribute__((ext_vector_type(4)));
typedef unsigned short u16;
typedef unsigned short u16x4 __attribute__((ext_vector_type(4)));
typedef unsigned int   u32;

__device__ __forceinline__ u16 f2bf(float f) {      // RNE float->bf16
    union { float f; unsigned u; } a; a.f = f;
    unsigned r = a.u + 0x7FFFu + ((a.u >> 16) & 1u);
    return (u16)(r >> 16);
}

// ---------------- fp32 -> bf16 convert ---------------------------------------
__global__ void cvt_f32_bf16(const float* __restrict__ in, u16* __restrict__ out, int n4) {
    int stride = gridDim.x * blockDim.x;
    for (int i = blockIdx.x * blockDim.x + threadIdx.x; i < n4; i += stride) {
        f32x4 v = ((const f32x4*)in)[i];
        u16x4 o;
        o[0] = f2bf(v[0]); o[1] = f2bf(v[1]); o[2] = f2bf(v[2]); o[3] = f2bf(v[3]);
        ((u16x4*)out)[i] = o;
    }
}

// ---------------- expand rel-pos bias table -> biasx[h][k 64][q 64] ----------
__global__ void bias_expand(const float* __restrict__ table, float* __restrict__ biasx) {
    int e = blockIdx.x * 256 + threadIdx.x;
    if (e >= HEADS*SEQ*SEQ) return;
    int h = e / (SEQ*SEQ), rem = e % (SEQ*SEQ);
    int k = rem / SEQ, q = rem % SEQ;
    int rq = q / 7, cq = q % 7, rk = k / 7, ck = k % 7;
    int idx = (rq - rk + 6)*13 + (cq - ck + 6);
    biasx[(h*64 + k)*64 + q] = table[idx*HEADS + h];
}

// ---------------- GEMM1: qkv with per-head scatter epilogue ------------------
// C = A[M,384]·Wqkv[1152,384]^T + b; writes qh/kh per-head row-major, vT transposed.
__global__ __launch_bounds__(256) void gemm_qkv_scatter(
    const u16* __restrict__ A, const u16* __restrict__ W,
    const float* __restrict__ bias,
    u16* __restrict__ qh, u16* __restrict__ kh, u16* __restrict__ vT,
    int M, int N, int K)
{
    __shared__ u16 Asm[128*32];
    __shared__ u16 Bsm[128*32];

    const int tid  = threadIdx.x;
    const int lane = tid & 63;
    const int wid  = tid >> 6;
    const int row0 = blockIdx.y * 128;
    const int col0 = blockIdx.x * 128;
    const int wr = (wid >> 1) * 64;
    const int wc = (wid & 1) * 64;

    f32x4 acc[4][4] = {};
    const int srow   = wid * 16 + (lane >> 2);
    const int kchunk = (lane & 3) * 8;

    for (int k0 = 0; k0 < K; k0 += 32) {
        __syncthreads();
        const u16* ga0 = A + (size_t)(row0 + srow) * K + k0 + kchunk;
        const u16* ga1 = A + (size_t)(row0 + 64 + srow) * K + k0 + kchunk;
        const u16* gb0 = W + (size_t)(col0 + srow) * K + k0 + kchunk;
        const u16* gb1 = W + (size_t)(col0 + 64 + srow) * K + k0 + kchunk;
        __builtin_amdgcn_global_load_lds((const __attribute__((address_space(1))) void*)ga0,
            (__attribute__((address_space(3))) void*)&Asm[(wid*16)*32], 16, 0, 0);
        __builtin_amdgcn_global_load_lds((const __attribute__((address_space(1))) void*)ga1,
            (__attribute__((address_space(3))) void*)&Asm[(64 + wid*16)*32], 16, 0, 0);
        __builtin_amdgcn_global_load_lds((const __attribute__((address_space(1))) void*)gb0,
            (__attribute__((address_space(3))) void*)&Bsm[(wid*16)*32], 16, 0, 0);
        __builtin_amdgcn_global_load_lds((const __attribute__((address_space(1))) void*)gb1,
            (__attribute__((address_space(3))) void*)&Bsm[(64 + wid*16)*32], 16, 0, 0);
        __syncthreads();

        bf16x8 a[4], b[4];
#pragma unroll
        for (int m = 0; m < 4; ++m)
            a[m] = *(const bf16x8*)&Asm[(wr + m*16 + (lane & 15))*32 + (lane >> 4)*8];
#pragma unroll
        for (int n = 0; n < 4; ++n)
            b[n] = *(const bf16x8*)&Bsm[(wc + n*16 + (lane & 15))*32 + (lane >> 4)*8];
#pragma unroll
        for (int m = 0; m < 4; ++m)
#pragma unroll
            for (int n = 0; n < 4; ++n)
                acc[m][n] = __builtin_amdgcn_mfma_f32_16x16x32_bf16(a[m], b[n], acc[m][n], 0, 0, 0);
    }

    const int rbase = row0 + wr + (lane >> 4) * 4;
    const int cbase = col0 + wc + (lane & 15);
    const int reg = (col0 >= 768) ? 2 : (col0 >= 384 ? 1 : 0);   // block-uniform
    float bv[4];
#pragma unroll
    for (int n = 0; n < 4; ++n) bv[n] = bias[cbase + n*16];

#pragma unroll
    for (int m = 0; m < 4; ++m)
#pragma unroll
        for (int j = 0; j < 4; ++j) {
            const int row = rbase + m*16 + j;
            const int b = row / 49;            // compiler magic-mul
            const int s = row - b*49;
#pragma unroll
            for (int n = 0; n < 4; ++n) {
                const int col = cbase + n*16;
                const u16 o = f2bf(acc[m][n][j] + bv[n]);
                if (reg == 0) {
                    const int h = col >> 5, d = col & 31;
                    qh[((size_t)(b*HEADS + h)*SEQ + s)*HD + d] = o;
                } else if (reg == 1) {
                    const int c = col - 384, h = c >> 5, d = c & 31;
                    kh[((size_t)(b*HEADS + h)*SEQ + s)*HD + d] = o;
                } else {
                    const int c = col - 768, h = c >> 5, d = c & 31;
                    vT[((size_t)(b*HEADS + h)*HD + d)*64 + s] = o;
                }
            }
        }
}

// ---------------- GEMM2: C[M,N] = A·W^T + bias, fp32 out ---------------------
__global__ __launch_bounds__(256) void gemm_bf16_nt(
    const u16* __restrict__ A, const u16* __restrict__ W,
    const float* __restrict__ bias, float* __restrict__ C,
    int M, int N, int K)
{
    __shared__ u16 Asm[128*32];
    __shared__ u16 Bsm[128*32];

    const int tid  = threadIdx.x;
    const int lane = tid & 63;
    const int wid  = tid >> 6;
    const int row0 = blockIdx.y * 128;
    const int col0 = blockIdx.x * 128;
    const int wr = (wid >> 1) * 64;
    const int wc = (wid & 1) * 64;

    f32x4 acc[4][4] = {};
    const int srow   = wid * 16 + (lane >> 2);
    const int kchunk = (lane & 3) * 8;

    for (int k0 = 0; k0 < K; k0 += 32) {
        __syncthreads();
        const u16* ga0 = A + (size_t)(row0 + srow) * K + k0 + kchunk;
        const u16* ga1 = A + (size_t)(row0 + 64 + srow) * K + k0 + kchunk;
        const u16* gb0 = W + (size_t)(col0 + srow) * K + k0 + kchunk;
        const u16* gb1 = W + (size_t)(col0 + 64 + srow) * K + k0 + kchunk;
        __builtin_amdgcn_global_load_lds((const __attribute__((address_space(1))) void*)ga0,
            (__attribute__((address_space(3))) void*)&Asm[(wid*16)*32], 16, 0, 0);
        __builtin_amdgcn_global_load_lds((const __attribute__((address_space(1))) void*)ga1,
            (__attribute__((address_space(3))) void*)&Asm[(64 + wid*16)*32], 16, 0, 0);
        __builtin_amdgcn_global_load_lds((const __attribute__((address_space(1))) void*)gb0,
            (__attribute__((address_space(3))) void*)&Bsm[(wid*16)*32], 16, 0, 0);
        __builtin_amdgcn_global_load_lds((const __attribute__((address_space(1))) void*)gb1,
            (__attribute__((address_space(3))) void*)&Bsm[(64 + wid*16)*32], 16, 0, 0);
        __syncthreads();

        bf16x8 a[4], b[4];
#pragma unroll
        for (int m = 0; m < 4; ++m)
            a[m] = *(const bf16x8*)&Asm[(wr + m*16 + (lane & 15))*32 + (lane >> 4)*8];
#pragma unroll
        for (int n = 0; n < 4; ++n)
            b[n] = *(const bf16x8*)&Bsm[(wc + n*16 + (lane & 15))*32 + (lane >> 4)*8];
#pragma unroll
        for (int m = 0; m < 4; ++m)
#pragma unroll
            for (int n = 0; n < 4; ++n)
                acc[m][n] = __builtin_amdgcn_mfma_f32_16x16x32_bf16(a[m], b[n], acc[m][n], 0, 0, 0);
    }

    const int rbase = row0 + wr + (lane >> 4) * 4;
    const int cbase = col0 + wc + (lane & 15);
#pragma unroll
    for (int n = 0; n < 4; ++n) {
        const int col = cbase + n*16;
        const float bvv = bias[col];
#pragma unroll
        for (int m = 0; m < 4; ++m)
#pragma unroll
            for (int j = 0; j < 4; ++j)
                C[(size_t)(rbase + m*16 + j)*N + col] = acc[m][n][j] + bvv;
    }
}

// ---------------- MFMA attention: block = 4 waves = one (b,h) ----------------
// Wave w computes S^T (64 keys x 16 queries, q-tile w) then PV for its 16 rows.
__global__ __launch_bounds__(256) void attn_mfma(
    const u16* __restrict__ qh, const u16* __restrict__ kh, const u16* __restrict__ vT,
    const float* __restrict__ mask, const float* __restrict__ biasx,
    u16* __restrict__ outb)
{
    const int h = blockIdx.x, b = blockIdx.y;
    const int tid = threadIdx.x, lane = tid & 63, w = tid >> 6;
    const int bh = b*HEADS + h;
    const int g = lane >> 4, r = lane & 15;

    __shared__ float m_raw[SEQ*SEQ];       // 9.6 KB
    __shared__ float comb[SEQ][52];        // 10.2 KB  (log2-domain bias+mask)
    __shared__ u16   p_sh[4][16][72];      // 9.2 KB   (per-wave P planes, padded)

    // stage mask coalesced
    const float* mb = mask + (size_t)b*SEQ*SEQ;
    for (int e = tid; e < SEQ*SEQ; e += 256) m_raw[e] = mb[e];
    __syncthreads();
    // comb[k][q] = log2e * (bias[h][k][q] + mask[q][k])
    const float* bx = biasx + h*4096;
    for (int e = tid; e < SEQ*SEQ; e += 256) {
        int k = e / 49, q = e - k*49;
        comb[k][q] = 1.4426950408889634f * (bx[k*64 + q] + m_raw[q*49 + k]);
    }
    __syncthreads();

    // ---- QK^T (S^T layout: row=key, col=query) ----
    const size_t qkbase = (size_t)bh * SEQ * HD;
    int sq = w*16 + r; sq = sq > 48 ? 48 : sq;
    const bf16x8 bq = *(const bf16x8*)&qh[qkbase + (size_t)sq*HD + g*8];
    bf16x8 ak[4];
#pragma unroll
    for (int kt = 0; kt < 4; ++kt) {
        int sk = kt*16 + r; sk = sk > 48 ? 48 : sk;
        ak[kt] = *(const bf16x8*)&kh[qkbase + (size_t)sk*HD + g*8];
    }
    f32x4 acc[4];
#pragma unroll
    for (int kt = 0; kt < 4; ++kt) {
        f32x4 z = {0.f, 0.f, 0.f, 0.f};
        acc[kt] = __builtin_amdgcn_mfma_f32_16x16x32_bf16(ak[kt], bq, z, 0, 0, 0);
    }

    // ---- scores (log2 domain) + softmax over keys ----
    const float scale2 = 0.25505235958f;   // 32^-0.5 * log2e
    const int qg = w*16 + r;
    const int qc = qg > 48 ? 48 : qg;      // clamp for LDS read (q>=49 rows dropped)
    float s[16];
#pragma unroll
    for (int kt = 0; kt < 4; ++kt)
#pragma unroll
        for (int j = 0; j < 4; ++j) {
            if (kt == 3 && j > 0) { s[kt*4+j] = -1e30f; continue; }  // k=49+4g.. masked
            const int k = kt*16 + g*4 + j;
            float v = acc[kt][j]*scale2 + comb[k][qc];
            if (kt == 3) v = (g == 0) ? v : -1e30f;                  // only k=48 valid
            s[kt*4+j] = v;
        }

    float mx = s[0];
#pragma unroll
    for (int i = 1; i < 16; ++i) mx = fmaxf(mx, s[i]);
    mx = fmaxf(mx, __shfl_xor(mx, 16));
    mx = fmaxf(mx, __shfl_xor(mx, 32));

    float p[16], sum = 0.f;
#pragma unroll
    for (int i = 0; i < 16; ++i) { p[i] = __builtin_amdgcn_exp2f(s[i] - mx); sum += p[i]; }
    sum += __shfl_xor(sum, 16);
    sum += __shfl_xor(sum, 32);
    const float inv = 1.0f / sum;

    // ---- P -> bf16 into wave-local LDS (A-operand layout) ----
    u32* prow = (u32*)&p_sh[w][r][0];
#pragma unroll
    for (int kt = 0; kt < 4; ++kt) {
        u32 w0 = (u32)f2bf(p[kt*4+0]) | ((u32)f2bf(p[kt*4+1]) << 16);
        u32 w1 = (u32)f2bf(p[kt*4+2]) | ((u32)f2bf(p[kt*4+3]) << 16);
        prow[kt*8 + g*2 + 0] = w0;
        prow[kt*8 + g*2 + 1] = w1;
    }
    asm volatile("s_waitcnt lgkmcnt(0)" ::: "memory");
    __builtin_amdgcn_sched_barrier(0);

    // ---- PV: out[16q x 32d] = P[16q x 64k] * vT^T ----
    bf16x8 pa[2];
#pragma unroll
    for (int ks = 0; ks < 2; ++ks)
        pa[ks] = *(const bf16x8*)&p_sh[w][r][g*8 + ks*32];
    const u16* vtb = vT + (size_t)bh * HD * 64;
    f32x4 po[2] = {};
#pragma unroll
    for (int n = 0; n < 2; ++n)
#pragma unroll
        for (int ks = 0; ks < 2; ++ks) {
            const bf16x8 bvv = *(const bf16x8*)&vtb[(size_t)(r + n*16)*64 + g*8 + ks*32];
            po[n] = __builtin_amdgcn_mfma_f32_16x16x32_bf16(pa[ks], bvv, po[n], 0, 0, 0);
        }

    // ---- scale by 1/sum (redistributed) + store ----
#pragma unroll
    for (int j = 0; j < 4; ++j) {
        const int qo = w*16 + g*4 + j;
        const float invj = __shfl(inv, g*4 + j);   // lane L<16 holds inv for q=16w+L
        if (qo < SEQ) {
            u16* dst = outb + (size_t)(b*SEQ + qo)*DIM + h*HD + r;
#pragma unroll
            for (int n = 0; n < 2; ++n) dst[n*16] = f2bf(po[n][j] * invj);
        }
    }
}

// ---------------- launch ----------------------------------------------------
extern "C" void kernel_launch(void* const* d_in, const int* in_sizes, int n_in,
                              void* d_out, int out_size, void* d_ws, size_t ws_size,
                              hipStream_t stream) {
    const float* hidden = (const float*)d_in[0];
    const float* mask   = (const float*)d_in[1];
    const float* w_qkv  = (const float*)d_in[2];
    const float* b_qkv  = (const float*)d_in[3];
    const float* w_out  = (const float*)d_in[4];
    const float* b_out  = (const float*)d_in[5];
    const float* table  = (const float*)d_in[6];
    float* out = (float*)d_out;

    char* ws = (char*)d_ws;
    u16* hiddenb = (u16*)ws;  ws += (size_t)ROWS*DIM*2;          // 77.1 MB (reused as attnb)
    u16* wqkvb   = (u16*)ws;  ws += (size_t)QKVD*DIM*2;
    u16* woutb   = (u16*)ws;  ws += (size_t)DIM*DIM*2;
    u16* qh      = (u16*)ws;  ws += (size_t)BATCH*HEADS*SEQ*HD*2;   // 77.1 MB
    u16* kh      = (u16*)ws;  ws += (size_t)BATCH*HEADS*SEQ*HD*2;   // 77.1 MB
    u16* vT      = (u16*)ws;  ws += (size_t)BATCH*HEADS*HD*64*2;    // 100.7 MB (k-padded)
    float* biasx = (float*)ws;                                      // 196.6 KB
    u16* attnb   = hiddenb;   // alias: hiddenb dead after GEMM1

    cvt_f32_bf16<<<2048, 256, 0, stream>>>(hidden, hiddenb, ROWS*DIM/4);
    cvt_f32_bf16<<<432,  256, 0, stream>>>(w_qkv,  wqkvb,   QKVD*DIM/4);
    cvt_f32_bf16<<<144,  256, 0, stream>>>(w_out,  woutb,   DIM*DIM/4);
    bias_expand<<<(HEADS*SEQ*SEQ + 255)/256, 256, 0, stream>>>(table, biasx);

    dim3 g1(QKVD/128, ROWS/128);   // (9, 784)
    gemm_qkv_scatter<<<g1, 256, 0, stream>>>(hiddenb, wqkvb, b_qkv, qh, kh, vT,
                                             ROWS, QKVD, DIM);

    dim3 ga(HEADS, BATCH);         // (12, 2048)
    attn_mfma<<<ga, 256, 0, stream>>>(qh, kh, vT, mask, biasx, attnb);

    dim3 g2(DIM/128, ROWS/128);    // (3, 784)
    gemm_bf16_nt<<<g2, 256, 0, stream>>>(attnb, woutb, b_out, out, ROWS, DIM, DIM);
}